// Round 8
// baseline (325.929 us; speedup 1.0000x reference)
//
#include <hip/hip_runtime.h>

typedef _Float16 half8 __attribute__((ext_vector_type(8)));
typedef _Float16 half4 __attribute__((ext_vector_type(4)));
typedef float f32x4 __attribute__((ext_vector_type(4)));

constexpr int B = 2, L = 2048, S = 2048, H = 16, E = 64, D = 64;
constexpr int BM = 64;   // Q rows per workgroup
constexpr int BN = 64;   // K/V rows per iteration
constexpr int LDT = 72;  // sK/sV leading dim (f16): 36-dword rows
constexpr int LDP = 72;  // sP leading dim (overlaid on sK region; 16B-aligned rows)
constexpr size_t BLHD = (size_t)B * L * H * D;
constexpr size_t BLH  = (size_t)B * L * H;

template <int NSPLIT>
__global__ __launch_bounds__(256, 8)
void fa_kernel(const float* __restrict__ Qg, const float* __restrict__ Kg,
               const float* __restrict__ Vg, const float* __restrict__ Mg,
               float* __restrict__ Oo, float* __restrict__ Lp)
{
    __shared__ _Float16 sK[BN][LDT];   // K tile [s][e]; sP overlays this region after B2
    __shared__ _Float16 sV[D][LDT];    // V^T [d][s]; 16B chunk swizzle: phys = cl ^ ((d>>3)&7)

    const int tid  = threadIdx.x;
    const int wave = tid >> 6;
    const int lane = tid & 63;
    const int quad = lane >> 4;
    const int lq   = lane & 15;

    // per-wave sP region overlaid on sK: [16 qrows][LDP]; wave base = 2304 B (576 dw, bank-neutral)
    _Float16* sPw = &sK[0][0] + wave * (16 * LDP);

    const int b  = blockIdx.y >> 4;
    const int h  = blockIdx.y & 15;
    const int q0 = blockIdx.x * BM;
    const int z  = blockIdx.z;                    // split index
    const int s_begin = z * (S / NSPLIT);
    const int nti = (S / NSPLIT) / BN;

    const int rowStride = H * E;  // 1024 floats
    const size_t qbase = ((size_t)b * L) * rowStride + h * E;
    const size_t kbase = ((size_t)b * S) * rowStride + h * E;

    const float cS = 0.125f * 1.44269504089f;  // scale*log2(e); fixed-shift exp2 softmax

    // ---- Q fragments, prescaled (B-operand: n=q=lq, k=e=ks*32+quad*8+j) ----
    half8 qf[2];
    {
        const float* qp = Qg + qbase + (size_t)(q0 + wave*16 + lq) * rowStride + quad*8;
        #pragma unroll
        for (int ks = 0; ks < 2; ++ks)
            #pragma unroll
            for (int j = 0; j < 8; ++j)
                qf[ks][j] = (_Float16)(qp[ks*32 + j] * cS);
    }

    const float* mrow = Mg + (size_t)(q0 + wave*16 + lq) * S + s_begin;

    float lsum = 0.f;
    f32x4 oacc[4];
    #pragma unroll
    for (int dt = 0; dt < 4; ++dt) oacc[dt] = (f32x4){0.f, 0.f, 0.f, 0.f};

    const int db = tid & 15;   // V-transpose staging decomposition
    const int sb = tid >> 4;
    const float* kbegin = Kg + kbase + (size_t)s_begin * rowStride;
    const float* vbase  = Vg + kbase + (size_t)(s_begin + sb*4) * rowStride + db*4;

    for (int t = 0; t < nti; ++t) {
        const int s0 = t * BN;  // relative to s_begin
        // ---- stage K tile (float4 -> half4, conflict-free) ----
        #pragma unroll
        for (int i = 0; i < 4; ++i) {
            int idx = i*256 + tid;
            int r = idx >> 4, c = (idx & 15)*4;
            const float4 kv = *(const float4*)(kbegin + (size_t)(s0 + r) * rowStride + c);
            half4 hk = {(_Float16)kv.x, (_Float16)kv.y, (_Float16)kv.z, (_Float16)kv.w};
            *(half4*)&sK[r][c] = hk;
        }
        // ---- stage V^T (4x4 register transpose + XOR swizzle, conflict-free) ----
        {
            float4 vr[4];
            #pragma unroll
            for (int i = 0; i < 4; ++i)
                vr[i] = *(const float4*)(vbase + (size_t)(s0 + i) * rowStride);
            const int off = (((sb >> 1) ^ (db >> 1)) << 3) + ((sb & 1) << 2);
            #pragma unroll
            for (int j = 0; j < 4; ++j) {
                half4 hv = { (_Float16)((&vr[0].x)[j]), (_Float16)((&vr[1].x)[j]),
                             (_Float16)((&vr[2].x)[j]), (_Float16)((&vr[3].x)[j]) };
                *(half4*)&sV[db*4 + j][off] = hv;
            }
        }
        __syncthreads();   // B1: staging visible

        // ---- mask gather (global, L2/L3-resident) ----
        float4 mv[4];
        #pragma unroll
        for (int nt = 0; nt < 4; ++nt)
            mv[nt] = *(const float4*)(mrow + s0 + nt*16 + quad*4);

        // ---- S^T = K Q^T (C-layout: row=s, col=q=lq) ----
        f32x4 sf[4];
        #pragma unroll
        for (int nt = 0; nt < 4; ++nt) {
            half8 kf0 = *(const half8*)&sK[nt*16 + lq][ 0 + quad*8];
            half8 kf1 = *(const half8*)&sK[nt*16 + lq][32 + quad*8];
            f32x4 acc = (f32x4){0.f, 0.f, 0.f, 0.f};
            acc = __builtin_amdgcn_mfma_f32_16x16x32_f16(kf0, qf[0], acc, 0, 0, 0);
            acc = __builtin_amdgcn_mfma_f32_16x16x32_f16(kf1, qf[1], acc, 0, 0, 0);
            sf[nt] = acc;
        }
        __syncthreads();   // B2: all waves done reading sK -> region reusable as sP

        // ---- p = exp2(logit + mask*cS); accumulate l; store to sP (overlay) ----
        #pragma unroll
        for (int nt = 0; nt < 4; ++nt) {
            half4 hp;
            #pragma unroll
            for (int r = 0; r < 4; ++r) {
                float lg = fmaf((&mv[nt].x)[r], cS, sf[nt][r]);
                float p  = __builtin_amdgcn_exp2f(lg);
                lsum += p;
                hp[r] = (_Float16)p;
            }
            *(half4*)&sPw[lq*LDP + nt*16 + quad*4] = hp;   // uniform 2 dw/bank
        }

        // ---- O += P V : A = sP rows (b128), B = sV rows (b128, swizzle-decoded) ----
        #pragma unroll
        for (int ks = 0; ks < 2; ++ks) {
            half8 pf = *(const half8*)&sPw[lq*LDP + ks*32 + quad*8];  // wave-private
            #pragma unroll
            for (int dt = 0; dt < 4; ++dt) {
                const int vrow = dt*16 + lq;
                const int phys = (ks*4 + quad) ^ ((vrow >> 3) & 7);
                half8 vf = *(const half8*)&sV[vrow][phys << 3];
                oacc[dt] = __builtin_amdgcn_mfma_f32_16x16x32_f16(pf, vf, oacc[dt], 0, 0, 0);
            }
        }
        __syncthreads();   // B3: sP/sV reads done before next staging overwrites
    }

    // ---- l reduction across quads (lanes lq,+16,+32,+48 share a q-row) ----
    lsum += __shfl_xor(lsum, 16);
    lsum += __shfl_xor(lsum, 32);

    if (NSPLIT == 1) {
        // normalized store direct to output
        #pragma unroll
        for (int r = 0; r < 4; ++r) {
            float l_bc = __shfl(lsum, quad*4 + r, 16);
            float inv = 1.f / l_bc;
            float* orow = Oo + qbase + (size_t)(q0 + wave*16 + quad*4 + r) * rowStride;
            #pragma unroll
            for (int dt = 0; dt < 4; ++dt)
                orow[dt*16 + lq] = oacc[dt][r] * inv;
        }
    } else {
        // unnormalized partial + per-row l
        float* obase = Oo + (size_t)z * BLHD;
        #pragma unroll
        for (int r = 0; r < 4; ++r) {
            float* orow = obase + qbase + (size_t)(q0 + wave*16 + quad*4 + r) * rowStride;
            #pragma unroll
            for (int dt = 0; dt < 4; ++dt)
                orow[dt*16 + lq] = oacc[dt][r];
        }
        if (quad == 0)
            Lp[(size_t)z * BLH + ((size_t)b * L + (q0 + wave*16 + lq)) * H + h] = lsum;
    }
}

__global__ __launch_bounds__(256)
void combine_kernel(const float* __restrict__ ws, float* __restrict__ Og)
{
    const size_t i4 = (size_t)blockIdx.x * 256 + threadIdx.x;  // over BLHD/4
    const float4 o0 = *(const float4*)(ws + i4 * 4);
    const float4 o1 = *(const float4*)(ws + BLHD + i4 * 4);
    const float* lp = ws + 2 * BLHD;
    const size_t q = i4 >> 4;                                  // (i4*4)/64
    const float inv = 1.f / (lp[q] + lp[BLH + q]);
    float4 o;
    o.x = (o0.x + o1.x) * inv;
    o.y = (o0.y + o1.y) * inv;
    o.z = (o0.z + o1.z) * inv;
    o.w = (o0.w + o1.w) * inv;
    *(float4*)(Og + i4 * 4) = o;
}

extern "C" void kernel_launch(void* const* d_in, const int* in_sizes, int n_in,
                              void* d_out, int out_size, void* d_ws, size_t ws_size,
                              hipStream_t stream) {
    const float* Qg = (const float*)d_in[0];
    const float* Kg = (const float*)d_in[1];
    const float* Vg = (const float*)d_in[2];
    const float* Mg = (const float*)d_in[3];
    float* Og = (float*)d_out;

    const size_t need = (2 * BLHD + 2 * BLH) * sizeof(float);
    if (ws_size >= need) {
        float* ws = (float*)d_ws;
        dim3 grid(L / BM, B * H, 2);   // 2048 WGs -> 8/CU
        fa_kernel<2><<<grid, 256, 0, stream>>>(Qg, Kg, Vg, Mg, ws, ws + 2 * BLHD);
        combine_kernel<<<dim3((unsigned)(BLHD / 4 / 256)), 256, 0, stream>>>(ws, Og);
    } else {
        dim3 grid(L / BM, B * H, 1);
        fa_kernel<1><<<grid, 256, 0, stream>>>(Qg, Kg, Vg, Mg, Og, nullptr);
    }
}

// Round 9
// 195.917 us; speedup vs baseline: 1.6636x; 1.6636x over previous
//
#include <hip/hip_runtime.h>

typedef _Float16 half8 __attribute__((ext_vector_type(8)));
typedef _Float16 half4 __attribute__((ext_vector_type(4)));
typedef float f32x4 __attribute__((ext_vector_type(4)));

constexpr int B = 2, L = 2048, S = 2048, H = 16, E = 64, D = 64;
constexpr int BM = 64;   // Q rows per workgroup
constexpr int BN = 64;   // K/V rows per iteration
constexpr int LDT = 72;  // f16 leading dim: 36-dword rows, 16B-aligned
constexpr int NTI = S / BN;

__global__ __launch_bounds__(256, 4)
void fa_kernel(const float* __restrict__ Qg, const float* __restrict__ Kg,
               const float* __restrict__ Vg, const float* __restrict__ Mg,
               float* __restrict__ Og)
{
    __shared__ _Float16 sK[BN][LDT];     // K tile [s][e]
    __shared__ _Float16 sV[D][LDT];      // V^T [d][s]; 16B chunk swizzle: phys = cl ^ ((d>>3)&7)
    __shared__ _Float16 sP[4][16][LDT];  // per-wave P [qrow][s]; b64 store / b128 read, conflict-free

    const int tid  = threadIdx.x;
    const int wave = tid >> 6;
    const int lane = tid & 63;
    const int quad = lane >> 4;
    const int lq   = lane & 15;

    // XCD-aware decode: WG i lands on XCD i%8 (round-robin heuristic).
    // Give each XCD 4 fixed (b,h) values -> its L2 K/V working set = 4 MB = L2 size;
    // co-resident same-qb WGs on an XCD share mask rows (mask is bh-broadcast).
    const int i  = blockIdx.x;
    const int bh = (i & 7) * 4 + ((i >> 3) & 3);
    const int qb = i >> 5;
    const int b  = bh >> 4;
    const int h  = bh & 15;
    const int q0 = qb * BM;

    const int rowStride = H * E;  // 1024 floats
    const size_t qbase = ((size_t)b * L) * rowStride + h * E;
    const size_t kbase = ((size_t)b * S) * rowStride + h * E;

    const float cS = 0.125f * 1.44269504089f;  // scale*log2(e); fixed-shift exp2 softmax

    // ---- Q fragments, prescaled (B-operand: n=q=lq, k=e=ks*32+quad*8+j) ----
    half8 qf[2];
    {
        const float* qp = Qg + qbase + (size_t)(q0 + wave*16 + lq) * rowStride + quad*8;
        #pragma unroll
        for (int ks = 0; ks < 2; ++ks)
            #pragma unroll
            for (int j = 0; j < 8; ++j)
                qf[ks][j] = (_Float16)(qp[ks*32 + j] * cS);
    }

    const float* mrow = Mg + (size_t)(q0 + wave*16 + lq) * S;

    float lsum = 0.f;
    f32x4 oacc[4];
    #pragma unroll
    for (int dt = 0; dt < 4; ++dt) oacc[dt] = (f32x4){0.f, 0.f, 0.f, 0.f};

    const int db = tid & 15;   // V-transpose staging decomposition
    const int sb = tid >> 4;
    const float* vbase = Vg + kbase + (size_t)(sb*4) * rowStride + db*4;

    for (int t = 0; t < NTI; ++t) {
        const int s0 = t * BN;
        // ---- stage K tile (float4 -> half4, conflict-free) ----
        #pragma unroll
        for (int ii = 0; ii < 4; ++ii) {
            int idx = ii*256 + tid;
            int r = idx >> 4, c = (idx & 15)*4;
            const float4 kv = *(const float4*)(Kg + kbase + (size_t)(s0 + r) * rowStride + c);
            half4 hk = {(_Float16)kv.x, (_Float16)kv.y, (_Float16)kv.z, (_Float16)kv.w};
            *(half4*)&sK[r][c] = hk;
        }
        // ---- stage V^T (4x4 register transpose + XOR swizzle, conflict-free) ----
        {
            float4 vr[4];
            #pragma unroll
            for (int j = 0; j < 4; ++j)
                vr[j] = *(const float4*)(vbase + (size_t)(s0 + j) * rowStride);
            const int off = (((sb >> 1) ^ (db >> 1)) << 3) + ((sb & 1) << 2);
            #pragma unroll
            for (int j = 0; j < 4; ++j) {
                half4 hv = { (_Float16)((&vr[0].x)[j]), (_Float16)((&vr[1].x)[j]),
                             (_Float16)((&vr[2].x)[j]), (_Float16)((&vr[3].x)[j]) };
                *(half4*)&sV[db*4 + j][off] = hv;
            }
        }
        __syncthreads();   // B1: staging visible

        // ---- mask gather (L2/L3-resident; shared with same-qb WGs on this XCD) ----
        float4 mv[4];
        #pragma unroll
        for (int nt = 0; nt < 4; ++nt)
            mv[nt] = *(const float4*)(mrow + s0 + nt*16 + quad*4);

        // ---- S^T = K Q^T (C-layout: row=s, col=q=lq) ----
        f32x4 sf[4];
        #pragma unroll
        for (int nt = 0; nt < 4; ++nt) {
            half8 kf0 = *(const half8*)&sK[nt*16 + lq][ 0 + quad*8];
            half8 kf1 = *(const half8*)&sK[nt*16 + lq][32 + quad*8];
            f32x4 acc = (f32x4){0.f, 0.f, 0.f, 0.f};
            acc = __builtin_amdgcn_mfma_f32_16x16x32_f16(kf0, qf[0], acc, 0, 0, 0);
            acc = __builtin_amdgcn_mfma_f32_16x16x32_f16(kf1, qf[1], acc, 0, 0, 0);
            sf[nt] = acc;
        }

        // ---- p = exp2(logit + mask*cS); accumulate l; packed b64 stores to sP ----
        #pragma unroll
        for (int nt = 0; nt < 4; ++nt) {
            half4 hp;
            #pragma unroll
            for (int r = 0; r < 4; ++r) {
                float lg = fmaf((&mv[nt].x)[r], cS, sf[nt][r]);
                float p  = __builtin_amdgcn_exp2f(lg);
                lsum += p;
                hp[r] = (_Float16)p;
            }
            *(half4*)&sP[wave][lq][nt*16 + quad*4] = hp;   // uniform 2 dw/bank
        }

        // ---- O += P V : A = sP rows (b128, wave-private), B = sV rows (b128) ----
        #pragma unroll
        for (int ks = 0; ks < 2; ++ks) {
            half8 pf = *(const half8*)&sP[wave][lq][ks*32 + quad*8];
            #pragma unroll
            for (int dt = 0; dt < 4; ++dt) {
                const int vrow = dt*16 + lq;
                const int phys = (ks*4 + quad) ^ ((vrow >> 3) & 7);
                half8 vf = *(const half8*)&sV[vrow][phys << 3];
                oacc[dt] = __builtin_amdgcn_mfma_f32_16x16x32_f16(pf, vf, oacc[dt], 0, 0, 0);
            }
        }
        __syncthreads();   // B2: all sK/sV reads done before next staging
    }

    // ---- l reduction across quads (lanes lq,+16,+32,+48 share a q-row) ----
    lsum += __shfl_xor(lsum, 16);
    lsum += __shfl_xor(lsum, 32);

    // ---- epilogue: O /= l, store fp32 ----
    #pragma unroll
    for (int r = 0; r < 4; ++r) {
        float l_bc = __shfl(lsum, quad*4 + r, 16);
        float inv = 1.f / l_bc;
        float* orow = Og + qbase + (size_t)(q0 + wave*16 + quad*4 + r) * rowStride;
        #pragma unroll
        for (int dt = 0; dt < 4; ++dt)
            orow[dt*16 + lq] = oacc[dt][r] * inv;
    }
}

extern "C" void kernel_launch(void* const* d_in, const int* in_sizes, int n_in,
                              void* d_out, int out_size, void* d_ws, size_t ws_size,
                              hipStream_t stream) {
    const float* Qg = (const float*)d_in[0];
    const float* Kg = (const float*)d_in[1];
    const float* Vg = (const float*)d_in[2];
    const float* Mg = (const float*)d_in[3];
    float* Og = (float*)d_out;
    dim3 grid((L / BM) * B * H);   // 1024 WGs, XCD-swizzled decode in-kernel
    fa_kernel<<<grid, 256, 0, stream>>>(Qg, Kg, Vg, Mg, Og);
}